// Round 8
// baseline (793.565 us; speedup 1.0000x reference)
//
#include <hip/hip_runtime.h>
#include <hip/hip_bf16.h>
#include <math.h>

typedef __hip_bfloat16 bf16;
typedef __attribute__((ext_vector_type(8))) short bf16x8;   // 8 bf16 = 4 VGPRs
typedef __attribute__((ext_vector_type(4))) short s16x4;
typedef __attribute__((ext_vector_type(4))) unsigned short u16x4;
typedef __attribute__((ext_vector_type(8))) unsigned short u16x8;
typedef __attribute__((ext_vector_type(4))) float f32x4;

#define CDIM 768
#define HDIM 64
#define NHEAD 12
#define TSEQ 1024
#define MROWS 4096   // B*T
#define HID 3072
#define QKVN 2304    // 3*CDIM

__device__ inline void gld16(const void* g, void* l) {
  __builtin_amdgcn_global_load_lds((const __attribute__((address_space(1))) void*)g,
                                   (__attribute__((address_space(3))) void*)l, 16, 0, 0);
}
__device__ inline short f2bs(float f) { bf16 h = __float2bfloat16(f); return *reinterpret_cast<short*>(&h); }

// ---------- weight transposes (+ qkv bias concat); grid = nl*3465 blocks ----------
// 64(k) x 32(n) tiles: coalesced dword loads -> LDS f32[64][33] (2-way banks, free) ->
// per-thread 8-elem pack -> ONE b128 store (full 128B transposed rows). 12KB/block.
__global__ __launch_bounds__(256) void k_trans(const float* __restrict__ Wq, const float* __restrict__ Wk,
                        const float* __restrict__ Wv, const float* __restrict__ Wp,
                        const float* __restrict__ W1, const float* __restrict__ W2,
                        const float* __restrict__ bq, const float* __restrict__ bk,
                        const float* __restrict__ bv,
                        bf16* __restrict__ wqkv, bf16* __restrict__ wtp,
                        bf16* __restrict__ wt1, bf16* __restrict__ wt2,
                        float* __restrict__ bqkv) {
  __shared__ float t[64][33];
  int blk = blockIdx.x;
  int l = blk / 3465; blk -= l * 3465;
  Wq += (size_t)l * CDIM * CDIM; Wk += (size_t)l * CDIM * CDIM;
  Wv += (size_t)l * CDIM * CDIM; Wp += (size_t)l * CDIM * CDIM;
  W1 += (size_t)l * CDIM * HID;  W2 += (size_t)l * HID * CDIM;
  bq += (size_t)l * CDIM; bk += (size_t)l * CDIM; bv += (size_t)l * CDIM;
  wqkv += (size_t)l * QKVN * CDIM; wtp += (size_t)l * CDIM * CDIM;
  wt1  += (size_t)l * CDIM * HID;  wt2 += (size_t)l * CDIM * HID;
  bqkv += (size_t)l * QKVN;
  int tid = threadIdx.x;
  if (blk >= 3456) {           // 9 trailing blocks: concat q,k,v biases into [2304]
    int i = (blk - 3456) * 256 + tid;
    if (i < QKVN) bqkv[i] = (i < CDIM) ? bq[i] : (i < 2 * CDIM) ? bk[i - CDIM] : bv[i - 2 * CDIM];
    return;
  }
  const float* src; bf16* dst; int K, N, n0, k0;
  if (blk < 864) {             // Wq|Wk|Wv: [768,768], 288 tiles each
    int w = blk / 288, id = blk % 288;
    src = (w == 0) ? Wq : (w == 1) ? Wk : Wv;
    dst = wqkv + (size_t)w * CDIM * CDIM;
    K = CDIM; N = CDIM;
    n0 = (id % 24) * 32; k0 = (id / 24) * 64;
  } else if (blk < 1152) {     // Wp
    int id = blk - 864;
    src = Wp; dst = wtp; K = CDIM; N = CDIM;
    n0 = (id % 24) * 32; k0 = (id / 24) * 64;
  } else if (blk < 2304) {     // W1: [768,3072]
    int id = blk - 1152;
    src = W1; dst = wt1; K = CDIM; N = HID;
    n0 = (id % 96) * 32; k0 = (id / 96) * 64;
  } else {                     // W2: [3072,768]
    int id = blk - 2304;
    src = W2; dst = wt2; K = HID; N = CDIM;
    n0 = (id % 24) * 32; k0 = (id / 24) * 64;
  }
  int rr = tid >> 5, cc = tid & 31;
  const float* sp = src + (size_t)(k0 + rr) * N + n0 + cc;
  #pragma unroll
  for (int i = 0; i < 8; i++)
    t[rr + 8 * i][cc] = sp[(size_t)(8 * i) * N];
  __syncthreads();
  int n = tid >> 3, kk = (tid & 7) * 8;
  u16x8 o;
  #pragma unroll
  for (int j = 0; j < 8; j++)
    o[j] = (unsigned short)f2bs(t[kk + j][n]);
  *(u16x8*)(dst + (size_t)(n0 + n) * K + k0 + kk) = o;
}

// ---------- layernorm: 4 rows/block, 1 wave/row, float4 loads, shuffle-only reduce ----------
__global__ __launch_bounds__(256) void k_ln(const float* __restrict__ h, const float* __restrict__ g,
                                            const float* __restrict__ b, bf16* __restrict__ out) {
  int wave = threadIdx.x >> 6, lane = threadIdx.x & 63;
  int row = blockIdx.x * 4 + wave;
  const float4* hr = (const float4*)(h + (size_t)row * CDIM);
  float4 v[3];
  float s = 0.f, ss = 0.f;
  #pragma unroll
  for (int i = 0; i < 3; i++) {
    v[i] = hr[lane * 3 + i];
    s  += v[i].x + v[i].y + v[i].z + v[i].w;
    ss += v[i].x * v[i].x + v[i].y * v[i].y + v[i].z * v[i].z + v[i].w * v[i].w;
  }
  #pragma unroll
  for (int off = 32; off > 0; off >>= 1) {
    s  += __shfl_xor(s, off, 64);
    ss += __shfl_xor(ss, off, 64);
  }
  float mu = s * (1.0f / CDIM);
  float var = ss * (1.0f / CDIM) - mu * mu;
  float rstd = rsqrtf(var + 1e-5f);
  const float4* gp = (const float4*)g;
  const float4* bp = (const float4*)b;
  s16x4* orow = (s16x4*)(out + (size_t)row * CDIM);
  #pragma unroll
  for (int i = 0; i < 3; i++) {
    float4 gg = gp[lane * 3 + i], bb = bp[lane * 3 + i];
    s16x4 o;
    o.x = f2bs((v[i].x - mu) * rstd * gg.x + bb.x);
    o.y = f2bs((v[i].y - mu) * rstd * gg.y + bb.y);
    o.z = f2bs((v[i].z - mu) * rstd * gg.z + bb.z);
    o.w = f2bs((v[i].w - mu) * rstd * gg.w + bb.w);
    orow[lane * 3 + i] = o;
  }
}

// ===== XOR-swizzled LDS tile helpers =====
// Tile [rows][64 bf16] = [rows][8 chunks of 8]. Row r, chunk c stored at slot c^(r&7).
// Staging (gld16): slot idx -> global chunk (idx&7)^((idx>>3)&7).
// Fragment read of logical chunk g from row r: LDS offset r*64 + (g^(r&7))*8.

// ---------- templated GEMM: out = A[M,K] @ Bt[N,K]^T + bias ----------
// EPI: 0 bias->bf16; 1 bias+gelu->bf16; 2 residual h+=acc+bias (fp32);
//      3 QKV: cols<1536 -> bf16 out; cols>=1536 (V) -> transposed vt[bh][d][t] (out2), b64 packed.
template <int BM, int BN, int EPI>
__global__ __launch_bounds__(256) void k_gemmT(const bf16* __restrict__ A, const bf16* __restrict__ Bt,
                                               const float* __restrict__ bias,
                                               void* __restrict__ outv, bf16* __restrict__ out2,
                                               int M, int N, int K) {
  constexpr int MR = BM / 32, NR = BN / 32;
  __shared__ __align__(16) bf16 As[BM * 64];
  __shared__ __align__(16) bf16 Bs[BN * 64];
  int tid = threadIdx.x;
  int m0 = blockIdx.x * BM, n0 = blockIdx.y * BN;
  int wave = tid >> 6, lane = tid & 63;
  int wr = wave >> 1, wc = wave & 1;
  int lrow = lane & 15, quad = lane >> 4;
  int sw = lrow & 7;
  f32x4 zz = {0.f, 0.f, 0.f, 0.f};
  f32x4 acc[MR][NR];
  #pragma unroll
  for (int i = 0; i < MR; i++)
    #pragma unroll
    for (int j = 0; j < NR; j++) acc[i][j] = zz;
  const bf16* Ag = A + (size_t)m0 * K;
  const bf16* Bg = Bt + (size_t)n0 * K;
  for (int k0 = 0; k0 < K; k0 += 64) {
    __syncthreads();
    #pragma unroll
    for (int i = 0; i < BM / 32; i++) {
      int idx = i * 256 + tid;
      int row = idx >> 3, c = idx & 7;
      gld16(Ag + (size_t)row * K + k0 + ((c ^ (row & 7)) * 8), As + idx * 8);
    }
    #pragma unroll
    for (int i = 0; i < BN / 32; i++) {
      int idx = i * 256 + tid;
      int row = idx >> 3, c = idx & 7;
      gld16(Bg + (size_t)row * K + k0 + ((c ^ (row & 7)) * 8), Bs + idx * 8);
    }
    __syncthreads();
    #pragma unroll
    for (int kc = 0; kc < 2; kc++) {
      int g = kc * 4 + quad;
      bf16x8 af[MR], bfr[NR];
      #pragma unroll
      for (int mi = 0; mi < MR; mi++)
        af[mi] = *(const bf16x8*)(As + (wr * (BM / 2) + mi * 16 + lrow) * 64 + ((g ^ sw) * 8));
      #pragma unroll
      for (int ni = 0; ni < NR; ni++)
        bfr[ni] = *(const bf16x8*)(Bs + (wc * (BN / 2) + ni * 16 + lrow) * 64 + ((g ^ sw) * 8));
      #pragma unroll
      for (int mi = 0; mi < MR; mi++)
        #pragma unroll
        for (int ni = 0; ni < NR; ni++)
          acc[mi][ni] = __builtin_amdgcn_mfma_f32_16x16x32_bf16(af[mi], bfr[ni], acc[mi][ni], 0, 0, 0);
    }
  }
  #pragma unroll
  for (int ni = 0; ni < NR; ni++) {
    int gc = n0 + wc * (BN / 2) + ni * 16 + lrow;
    float bval = bias[gc];
    #pragma unroll
    for (int mi = 0; mi < MR; mi++) {
      if (EPI == 3 && gc >= 1536) {          // V third -> vt[bh][d][t], packed b64 (uniform per tile)
        int dcol = gc - 1536, h2 = dcol >> 6, dd = dcol & 63;
        int grow0 = m0 + wr * (BM / 2) + mi * 16 + quad * 4;
        u16x4 o;
        o.x = (unsigned short)f2bs(acc[mi][ni][0] + bval);
        o.y = (unsigned short)f2bs(acc[mi][ni][1] + bval);
        o.z = (unsigned short)f2bs(acc[mi][ni][2] + bval);
        o.w = (unsigned short)f2bs(acc[mi][ni][3] + bval);
        int bh2 = (grow0 >> 10) * NHEAD + h2;
        *(u16x4*)(out2 + ((size_t)bh2 * HDIM + dd) * TSEQ + (grow0 & 1023)) = o;
      } else {
        #pragma unroll
        for (int r = 0; r < 4; r++) {
          int grow = m0 + wr * (BM / 2) + mi * 16 + quad * 4 + r;
          float vv = acc[mi][ni][r] + bval;
          if (EPI == 1) vv = 0.5f * vv * (1.0f + erff(vv * 0.70710678118654752f));
          if (EPI == 2) {
            float* hp = (float*)outv + (size_t)grow * N + gc;
            *hp = *hp + vv;
          } else {
            ((bf16*)outv)[(size_t)grow * N + gc] = __float2bfloat16(vv);
          }
        }
      }
    }
  }
}

// ---------- MFMA flash attention, swapped QK^T, V pre-transposed ----------
// grid (48, 16); 4 waves; wave owns 16 q rows. mask: (k%256) <= (q%256).
// Swapped S^T = mfma(K, Q): lane (lrow,quad) holds q=lrow, keys {sub*16+quad*4+r}.
// Softmax: 15 in-reg ops + 2 shfl; P -> per-wave LDS as 4 b64 swizzled stores; PV unchanged layout.
__global__ __launch_bounds__(256) void k_attn(const bf16* __restrict__ qkv, const bf16* __restrict__ vt,
                                              bf16* __restrict__ y) {
  int bh = blockIdx.x;
  int b = bh / NHEAD, hh = bh % NHEAD;
  int qc = blockIdx.y ^ 3;                 // heavy-first: qcmod=192 blocks dispatch first
  int tid = threadIdx.x;
  int wave = tid >> 6, lane = tid & 63;
  int lrow = lane & 15, quad = lane >> 4;
  int sw = lrow & 7;
  int q0 = qc * 64 + wave * 16;
  int qmod = q0 & 255;
  int qcmod = (qc * 64) & 255;

  const size_t rstride = QKVN;
  const bf16* qbase = qkv + (size_t)(b * TSEQ) * rstride + hh * HDIM;
  const bf16* kbase = qbase + CDIM;
  const bf16* vtb = vt + (size_t)bh * HDIM * TSEQ;

  bf16x8 qf[2];
  #pragma unroll
  for (int kc = 0; kc < 2; kc++)
    qf[kc] = *(const bf16x8*)(qbase + (size_t)(q0 + lrow) * rstride + kc * 32 + quad * 8);

  f32x4 zz = {0.f, 0.f, 0.f, 0.f};
  f32x4 Oacc[4];
  #pragma unroll
  for (int j = 0; j < 4; j++) Oacc[j] = zz;
  float m = -1e30f, l = 0.f;

  __shared__ __align__(16) bf16 Ks[64 * 64];       // [key][d], swizzled chunks
  __shared__ __align__(16) bf16 Vs[64 * 64];       // [d][key] from vt, swizzled chunks
  __shared__ __align__(16) bf16 Pl[4][16 * 64];    // per-wave P [q][key], swizzled chunks

  for (int kt = 0; kt < 16; kt++) {
    int k0 = kt * 64;
    int kmod = k0 & 255;
    if (kmod > qcmod + 63) continue;       // block-uniform skip
    __syncthreads();
    #pragma unroll
    for (int i = 0; i < 2; i++) {
      int idx = i * 256 + tid;
      int row = idx >> 3, c = idx & 7;
      gld16(kbase + (size_t)(k0 + row) * rstride + ((c ^ (row & 7)) * 8), Ks + idx * 8);
      gld16(vtb + (size_t)row * TSEQ + k0 + ((c ^ (row & 7)) * 8), Vs + idx * 8);
    }
    __syncthreads();
    if (kmod > qmod + 15) continue;        // wave-uniform skip

    // S^T = K @ Q^T: lane holds q=lrow, keys sub*16+quad*4+r
    f32x4 s[4];
    #pragma unroll
    for (int sub = 0; sub < 4; sub++) {
      s[sub] = zz;
      #pragma unroll
      for (int kc = 0; kc < 2; kc++) {
        int g = kc * 4 + quad;
        bf16x8 kf = *(const bf16x8*)(Ks + (sub * 16 + lrow) * 64 + ((g ^ sw) * 8));
        s[sub] = __builtin_amdgcn_mfma_f32_16x16x32_bf16(kf, qf[kc], s[sub], 0, 0, 0);
      }
    }
    bool partial = (kmod + 63 > qmod);
    int qrel = qmod + lrow;
    #pragma unroll
    for (int sub = 0; sub < 4; sub++)
      #pragma unroll
      for (int r = 0; r < 4; r++) {
        float sv = s[sub][r] * 0.125f;     // 1/sqrt(64)
        if (partial && (kmod + sub * 16 + quad * 4 + r > qrel)) sv = -1e30f;
        s[sub][r] = sv;
      }
    // softmax: lane owns its q-row's 16 keys; quad-reduce via 2 shuffles
    float mx = fmaxf(fmaxf(fmaxf(s[0][0], s[0][1]), fmaxf(s[0][2], s[0][3])),
                     fmaxf(fmaxf(s[1][0], s[1][1]), fmaxf(s[1][2], s[1][3])));
    mx = fmaxf(mx, fmaxf(fmaxf(fmaxf(s[2][0], s[2][1]), fmaxf(s[2][2], s[2][3])),
                         fmaxf(fmaxf(s[3][0], s[3][1]), fmaxf(s[3][2], s[3][3]))));
    mx = fmaxf(mx, __shfl_xor(mx, 16, 64));
    mx = fmaxf(mx, __shfl_xor(mx, 32, 64));
    float mnew = fmaxf(m, mx);
    float alpha = __expf(m - mnew);
    m = mnew;
    float p[4][4];
    float rs = 0.f;
    #pragma unroll
    for (int sub = 0; sub < 4; sub++)
      #pragma unroll
      for (int r = 0; r < 4; r++) {
        p[sub][r] = __expf(s[sub][r] - mnew);
        rs += p[sub][r];
      }
    rs += __shfl_xor(rs, 16, 64);
    rs += __shfl_xor(rs, 32, 64);
    l = l * alpha + rs;
    // rescale O (alpha lives on lane lrow=q; fetch per C-row q=quad*4+r)
    #pragma unroll
    for (int r = 0; r < 4; r++) {
      float ar = __shfl(alpha, quad * 4 + r, 16);
      #pragma unroll
      for (int j = 0; j < 4; j++) Oacc[j][r] *= ar;
    }
    // P -> per-wave LDS: 4 x b64 swizzled stores (keys sub*16+quad*4+0..3 at row lrow)
    bf16* Pw = (bf16*)Pl[wave];
    #pragma unroll
    for (int sub = 0; sub < 4; sub++) {
      u16x4 o;
      o.x = (unsigned short)f2bs(p[sub][0]);
      o.y = (unsigned short)f2bs(p[sub][1]);
      o.z = (unsigned short)f2bs(p[sub][2]);
      o.w = (unsigned short)f2bs(p[sub][3]);
      int ch = sub * 2 + (quad >> 1);
      *(u16x4*)(Pw + lrow * 64 + ((ch ^ sw) * 8) + 4 * (quad & 1)) = o;
    }
    bf16x8 pf[2];
    #pragma unroll
    for (int kc = 0; kc < 2; kc++) {
      int g = kc * 4 + quad;
      pf[kc] = *(const bf16x8*)(Pw + lrow * 64 + ((g ^ sw) * 8));
    }
    #pragma unroll
    for (int j = 0; j < 4; j++)
      #pragma unroll
      for (int kc = 0; kc < 2; kc++) {
        int g = kc * 4 + quad;
        bf16x8 vf = *(const bf16x8*)(Vs + (j * 16 + lrow) * 64 + ((g ^ sw) * 8));
        Oacc[j] = __builtin_amdgcn_mfma_f32_16x16x32_bf16(pf[kc], vf, Oacc[j], 0, 0, 0);
      }
  }
  #pragma unroll
  for (int r = 0; r < 4; r++) {
    float linv = 1.0f / __shfl(l, quad * 4 + r, 16);
    bf16* yp = y + (size_t)(b * TSEQ + q0 + quad * 4 + r) * CDIM + hh * HDIM;
    #pragma unroll
    for (int j = 0; j < 4; j++)
      yp[j * 16 + lrow] = __float2bfloat16(Oacc[j][r] * linv);
  }
}

extern "C" void kernel_launch(void* const* d_in, const int* in_sizes, int n_in,
                              void* d_out, int out_size, void* d_ws, size_t ws_size,
                              hipStream_t stream) {
  const float* x    = (const float*)d_in[0];
  const float* ln1g = (const float*)d_in[1];
  const float* ln1b = (const float*)d_in[2];
  const float* Wq   = (const float*)d_in[3];
  const float* bq   = (const float*)d_in[4];
  const float* Wk   = (const float*)d_in[5];
  const float* bk   = (const float*)d_in[6];
  const float* Wv   = (const float*)d_in[7];
  const float* bv   = (const float*)d_in[8];
  const float* Wp   = (const float*)d_in[9];
  const float* bp   = (const float*)d_in[10];
  const float* ln2g = (const float*)d_in[11];
  const float* ln2b = (const float*)d_in[12];
  const float* W1   = (const float*)d_in[13];
  const float* b1   = (const float*)d_in[14];
  const float* W2   = (const float*)d_in[15];
  const float* b2   = (const float*)d_in[16];

  char* ws = (char*)d_ws;
  size_t off = 0;
  float* h    = (float*)(ws + off); off += (size_t)MROWS * CDIM * 4;
  bf16* a     = (bf16*)(ws + off);  off += (size_t)MROWS * CDIM * 2;
  bf16* qkvb  = (bf16*)(ws + off);  off += (size_t)MROWS * QKVN * 2;
  bf16* yb    = (bf16*)(ws + off);  off += (size_t)MROWS * CDIM * 2;
  bf16* vt    = (bf16*)(ws + off);  off += (size_t)4 * NHEAD * HDIM * TSEQ * 2;  // [48][64][1024]
  bf16* m1    = qkvb;  // alias: MLP hidden [4096,3072] overlays qkvb+yb (both dead by then)

  const size_t szQkv = (size_t)QKVN * CDIM * 2;
  const size_t szP   = (size_t)CDIM * CDIM * 2;
  const size_t szW1  = (size_t)CDIM * HID * 2;
  const size_t szW2  = (size_t)CDIM * HID * 2;
  const size_t szB   = (size_t)QKVN * 4;
  const size_t wlayer = szQkv + szP + szW1 + szW2 + szB;
  bool hoist = ws_size >= off + 4 * wlayer + 4096;
  int nW = hoist ? 4 : 1;

  bf16* wqkv  = (bf16*)(ws + off);  off += nW * szQkv;
  bf16* wtp   = (bf16*)(ws + off);  off += nW * szP;
  bf16* wt1   = (bf16*)(ws + off);  off += nW * szW1;
  bf16* wt2   = (bf16*)(ws + off);  off += nW * szW2;
  float* bqkv = (float*)(ws + off); off += nW * szB;

  int n = MROWS * CDIM;
  hipMemcpyAsync(h, x, (size_t)n * sizeof(float), hipMemcpyDeviceToDevice, stream);

  if (hoist)
    k_trans<<<dim3(4 * 3465), dim3(256), 0, stream>>>(Wq, Wk, Wv, Wp, W1, W2, bq, bk, bv,
                                                      wqkv, wtp, wt1, wt2, bqkv);

  for (int l = 0; l < 4; l++) {
    int wl = hoist ? l : 0;
    if (!hoist)
      k_trans<<<dim3(3465), dim3(256), 0, stream>>>(
          Wq + (size_t)l * CDIM * CDIM, Wk + (size_t)l * CDIM * CDIM,
          Wv + (size_t)l * CDIM * CDIM, Wp + (size_t)l * CDIM * CDIM,
          W1 + (size_t)l * CDIM * HID, W2 + (size_t)l * HID * CDIM,
          bq + (size_t)l * CDIM, bk + (size_t)l * CDIM, bv + (size_t)l * CDIM,
          wqkv, wtp, wt1, wt2, bqkv);
    const bf16* wqkvl = wqkv + (size_t)wl * QKVN * CDIM;
    const bf16* wtpl  = wtp  + (size_t)wl * CDIM * CDIM;
    const bf16* wt1l  = wt1  + (size_t)wl * CDIM * HID;
    const bf16* wt2l  = wt2  + (size_t)wl * CDIM * HID;
    const float* bqkvl = bqkv + (size_t)wl * QKVN;

    k_ln<<<dim3(MROWS / 4), dim3(256), 0, stream>>>(h, ln1g + l * CDIM, ln1b + l * CDIM, a);

    // QKV: q,k -> qkvb; v -> vt transposed
    k_gemmT<64, 128, 3><<<dim3(MROWS / 64, QKVN / 128), dim3(256), 0, stream>>>(
        a, wqkvl, bqkvl, qkvb, vt, MROWS, QKVN, CDIM);

    k_attn<<<dim3(4 * NHEAD, 16), dim3(256), 0, stream>>>(qkvb, vt, yb);

    // attn proj + residual: h += yb @ Wp^T + bp
    k_gemmT<64, 64, 2><<<dim3(MROWS / 64, CDIM / 64), dim3(256), 0, stream>>>(
        yb, wtpl, bp + (size_t)l * CDIM, h, nullptr, MROWS, CDIM, CDIM);

    k_ln<<<dim3(MROWS / 4), dim3(256), 0, stream>>>(h, ln2g + l * CDIM, ln2b + l * CDIM, a);

    // MLP up + gelu
    k_gemmT<64, 128, 1><<<dim3(MROWS / 64, HID / 128), dim3(256), 0, stream>>>(
        a, wt1l, b1 + (size_t)l * HID, m1, nullptr, MROWS, HID, CDIM);

    // MLP down + residual
    k_gemmT<64, 64, 2><<<dim3(MROWS / 64, CDIM / 64), dim3(256), 0, stream>>>(
        m1, wt2l, b2 + (size_t)l * CDIM, h, nullptr, MROWS, CDIM, HID);
  }

  hipMemcpyAsync(d_out, h, (size_t)n * sizeof(float), hipMemcpyDeviceToDevice, stream);
}

// Round 9
// 758.642 us; speedup vs baseline: 1.0460x; 1.0460x over previous
//
#include <hip/hip_runtime.h>
#include <hip/hip_bf16.h>
#include <math.h>

typedef __hip_bfloat16 bf16;
typedef __attribute__((ext_vector_type(8))) short bf16x8;   // 8 bf16 = 4 VGPRs
typedef __attribute__((ext_vector_type(4))) short s16x4;
typedef __attribute__((ext_vector_type(4))) unsigned short u16x4;
typedef __attribute__((ext_vector_type(8))) unsigned short u16x8;
typedef __attribute__((ext_vector_type(4))) float f32x4;

#define CDIM 768
#define HDIM 64
#define NHEAD 12
#define TSEQ 1024
#define MROWS 4096   // B*T
#define HID 3072
#define QKVN 2304    // 3*CDIM

__device__ inline void gld16(const void* g, void* l) {
  __builtin_amdgcn_global_load_lds((const __attribute__((address_space(1))) void*)g,
                                   (__attribute__((address_space(3))) void*)l, 16, 0, 0);
}
__device__ inline short f2bs(float f) { bf16 h = __float2bfloat16(f); return *reinterpret_cast<short*>(&h); }

// ---------- weight transposes (+ qkv bias concat); grid = nl*1737 blocks ----------
// 64(k) x 64(n) tiles: 16 coalesced dword loads/thread (64B in flight) -> LDS f32[64][65]
// (2-way banks on both phases, free) -> 2 contiguous u16x8 stores/thread (32B; 4 thr/row).
__global__ __launch_bounds__(256) void k_trans(const float* __restrict__ Wq, const float* __restrict__ Wk,
                        const float* __restrict__ Wv, const float* __restrict__ Wp,
                        const float* __restrict__ W1, const float* __restrict__ W2,
                        const float* __restrict__ bq, const float* __restrict__ bk,
                        const float* __restrict__ bv,
                        bf16* __restrict__ wqkv, bf16* __restrict__ wtp,
                        bf16* __restrict__ wt1, bf16* __restrict__ wt2,
                        float* __restrict__ bqkv) {
  __shared__ float t[64][65];
  int blk = blockIdx.x;
  int l = blk / 1737; blk -= l * 1737;
  Wq += (size_t)l * CDIM * CDIM; Wk += (size_t)l * CDIM * CDIM;
  Wv += (size_t)l * CDIM * CDIM; Wp += (size_t)l * CDIM * CDIM;
  W1 += (size_t)l * CDIM * HID;  W2 += (size_t)l * HID * CDIM;
  bq += (size_t)l * CDIM; bk += (size_t)l * CDIM; bv += (size_t)l * CDIM;
  wqkv += (size_t)l * QKVN * CDIM; wtp += (size_t)l * CDIM * CDIM;
  wt1  += (size_t)l * CDIM * HID;  wt2 += (size_t)l * CDIM * HID;
  bqkv += (size_t)l * QKVN;
  int tid = threadIdx.x;
  if (blk >= 1728) {           // 9 trailing blocks: concat q,k,v biases into [2304]
    int i = (blk - 1728) * 256 + tid;
    if (i < QKVN) bqkv[i] = (i < CDIM) ? bq[i] : (i < 2 * CDIM) ? bk[i - CDIM] : bv[i - 2 * CDIM];
    return;
  }
  const float* src; bf16* dst; int K, N, n0, k0;
  if (blk < 432) {             // Wq|Wk|Wv: [768,768], 144 tiles each
    int w = blk / 144, id = blk % 144;
    src = (w == 0) ? Wq : (w == 1) ? Wk : Wv;
    dst = wqkv + (size_t)w * CDIM * CDIM;
    K = CDIM; N = CDIM;
    n0 = (id % 12) * 64; k0 = (id / 12) * 64;
  } else if (blk < 576) {      // Wp
    int id = blk - 432;
    src = Wp; dst = wtp; K = CDIM; N = CDIM;
    n0 = (id % 12) * 64; k0 = (id / 12) * 64;
  } else if (blk < 1152) {     // W1: [768,3072]
    int id = blk - 576;
    src = W1; dst = wt1; K = CDIM; N = HID;
    n0 = (id % 48) * 64; k0 = (id / 48) * 64;
  } else {                     // W2: [3072,768]
    int id = blk - 1152;
    src = W2; dst = wt2; K = HID; N = CDIM;
    n0 = (id % 12) * 64; k0 = (id / 12) * 64;
  }
  int c = tid & 63, r0 = tid >> 6;
  const float* sp = src + (size_t)(k0 + r0) * N + n0 + c;
  #pragma unroll
  for (int i = 0; i < 16; i++)
    t[r0 + 4 * i][c] = sp[(size_t)(4 * i) * N];
  __syncthreads();
  int n = tid >> 2, kk = (tid & 3) * 16;
  bf16* dp = dst + (size_t)(n0 + n) * K + k0 + kk;
  #pragma unroll
  for (int s2 = 0; s2 < 2; s2++) {
    u16x8 o;
    #pragma unroll
    for (int j = 0; j < 8; j++)
      o[j] = (unsigned short)f2bs(t[kk + 8 * s2 + j][n]);
    *(u16x8*)(dp + 8 * s2) = o;
  }
}

// ---------- layernorm: 4 rows/block, 1 wave/row, float4 loads, shuffle-only reduce ----------
__global__ __launch_bounds__(256) void k_ln(const float* __restrict__ h, const float* __restrict__ g,
                                            const float* __restrict__ b, bf16* __restrict__ out) {
  int wave = threadIdx.x >> 6, lane = threadIdx.x & 63;
  int row = blockIdx.x * 4 + wave;
  const float4* hr = (const float4*)(h + (size_t)row * CDIM);
  float4 v[3];
  float s = 0.f, ss = 0.f;
  #pragma unroll
  for (int i = 0; i < 3; i++) {
    v[i] = hr[lane * 3 + i];
    s  += v[i].x + v[i].y + v[i].z + v[i].w;
    ss += v[i].x * v[i].x + v[i].y * v[i].y + v[i].z * v[i].z + v[i].w * v[i].w;
  }
  #pragma unroll
  for (int off = 32; off > 0; off >>= 1) {
    s  += __shfl_xor(s, off, 64);
    ss += __shfl_xor(ss, off, 64);
  }
  float mu = s * (1.0f / CDIM);
  float var = ss * (1.0f / CDIM) - mu * mu;
  float rstd = rsqrtf(var + 1e-5f);
  const float4* gp = (const float4*)g;
  const float4* bp = (const float4*)b;
  s16x4* orow = (s16x4*)(out + (size_t)row * CDIM);
  #pragma unroll
  for (int i = 0; i < 3; i++) {
    float4 gg = gp[lane * 3 + i], bb = bp[lane * 3 + i];
    s16x4 o;
    o.x = f2bs((v[i].x - mu) * rstd * gg.x + bb.x);
    o.y = f2bs((v[i].y - mu) * rstd * gg.y + bb.y);
    o.z = f2bs((v[i].z - mu) * rstd * gg.z + bb.z);
    o.w = f2bs((v[i].w - mu) * rstd * gg.w + bb.w);
    orow[lane * 3 + i] = o;
  }
}

// ===== XOR-swizzled LDS tile helpers =====
// Tile [rows][64 bf16] = [rows][8 chunks of 8]. Row r, chunk c stored at slot c^(r&7).
// Staging (gld16): slot idx -> global chunk (idx&7)^((idx>>3)&7).
// Fragment read of logical chunk g from row r: LDS offset r*64 + (g^(r&7))*8.

// ---------- templated GEMM: out = A[M,K] @ Bt[N,K]^T + bias ----------
// EPI: 0 bias->bf16; 1 bias+gelu->bf16; 2 residual h+=acc+bias (fp32);
//      3 QKV: cols<1536 -> bf16 out; cols>=1536 (V) -> transposed vt[bh][d][t] (out2), b64 packed.
template <int BM, int BN, int EPI>
__global__ __launch_bounds__(256) void k_gemmT(const bf16* __restrict__ A, const bf16* __restrict__ Bt,
                                               const float* __restrict__ bias,
                                               void* __restrict__ outv, bf16* __restrict__ out2,
                                               int M, int N, int K) {
  constexpr int MR = BM / 32, NR = BN / 32;
  __shared__ __align__(16) bf16 As[BM * 64];
  __shared__ __align__(16) bf16 Bs[BN * 64];
  int tid = threadIdx.x;
  int m0 = blockIdx.x * BM, n0 = blockIdx.y * BN;
  int wave = tid >> 6, lane = tid & 63;
  int wr = wave >> 1, wc = wave & 1;
  int lrow = lane & 15, quad = lane >> 4;
  int sw = lrow & 7;
  f32x4 zz = {0.f, 0.f, 0.f, 0.f};
  f32x4 acc[MR][NR];
  #pragma unroll
  for (int i = 0; i < MR; i++)
    #pragma unroll
    for (int j = 0; j < NR; j++) acc[i][j] = zz;
  const bf16* Ag = A + (size_t)m0 * K;
  const bf16* Bg = Bt + (size_t)n0 * K;
  for (int k0 = 0; k0 < K; k0 += 64) {
    __syncthreads();
    #pragma unroll
    for (int i = 0; i < BM / 32; i++) {
      int idx = i * 256 + tid;
      int row = idx >> 3, c = idx & 7;
      gld16(Ag + (size_t)row * K + k0 + ((c ^ (row & 7)) * 8), As + idx * 8);
    }
    #pragma unroll
    for (int i = 0; i < BN / 32; i++) {
      int idx = i * 256 + tid;
      int row = idx >> 3, c = idx & 7;
      gld16(Bg + (size_t)row * K + k0 + ((c ^ (row & 7)) * 8), Bs + idx * 8);
    }
    __syncthreads();
    #pragma unroll
    for (int kc = 0; kc < 2; kc++) {
      int g = kc * 4 + quad;
      bf16x8 af[MR], bfr[NR];
      #pragma unroll
      for (int mi = 0; mi < MR; mi++)
        af[mi] = *(const bf16x8*)(As + (wr * (BM / 2) + mi * 16 + lrow) * 64 + ((g ^ sw) * 8));
      #pragma unroll
      for (int ni = 0; ni < NR; ni++)
        bfr[ni] = *(const bf16x8*)(Bs + (wc * (BN / 2) + ni * 16 + lrow) * 64 + ((g ^ sw) * 8));
      #pragma unroll
      for (int mi = 0; mi < MR; mi++)
        #pragma unroll
        for (int ni = 0; ni < NR; ni++)
          acc[mi][ni] = __builtin_amdgcn_mfma_f32_16x16x32_bf16(af[mi], bfr[ni], acc[mi][ni], 0, 0, 0);
    }
  }
  #pragma unroll
  for (int ni = 0; ni < NR; ni++) {
    int gc = n0 + wc * (BN / 2) + ni * 16 + lrow;
    float bval = bias[gc];
    #pragma unroll
    for (int mi = 0; mi < MR; mi++) {
      if (EPI == 3 && gc >= 1536) {          // V third -> vt[bh][d][t], packed b64 (uniform per tile)
        int dcol = gc - 1536, h2 = dcol >> 6, dd = dcol & 63;
        int grow0 = m0 + wr * (BM / 2) + mi * 16 + quad * 4;
        u16x4 o;
        o.x = (unsigned short)f2bs(acc[mi][ni][0] + bval);
        o.y = (unsigned short)f2bs(acc[mi][ni][1] + bval);
        o.z = (unsigned short)f2bs(acc[mi][ni][2] + bval);
        o.w = (unsigned short)f2bs(acc[mi][ni][3] + bval);
        int bh2 = (grow0 >> 10) * NHEAD + h2;
        *(u16x4*)(out2 + ((size_t)bh2 * HDIM + dd) * TSEQ + (grow0 & 1023)) = o;
      } else {
        #pragma unroll
        for (int r = 0; r < 4; r++) {
          int grow = m0 + wr * (BM / 2) + mi * 16 + quad * 4 + r;
          float vv = acc[mi][ni][r] + bval;
          if (EPI == 1) {
            // tanh-form gelu via sigmoid: x*sigma(1.5958*(x+0.044715x^3)); |err| vs erf-gelu
            // <= ~1e-3 abs — below bf16 quantization of m1. Much cheaper than erff.
            float u = 1.5957691216f * (vv + 0.044715f * vv * vv * vv);
            vv = vv / (1.0f + __expf(-u));
          }
          if (EPI == 2) {
            float* hp = (float*)outv + (size_t)grow * N + gc;
            *hp = *hp + vv;
          } else {
            ((bf16*)outv)[(size_t)grow * N + gc] = __float2bfloat16(vv);
          }
        }
      }
    }
  }
}

// ---------- MFMA flash attention, swapped QK^T, V pre-transposed ----------
// grid (48, 16); 4 waves; wave owns 16 q rows. mask: (k%256) <= (q%256).
// Swapped S^T = mfma(K, Q): lane (lrow,quad) holds q=lrow, keys {sub*16+quad*4+r}.
// Softmax: 15 in-reg ops + 2 shfl; P -> per-wave LDS as 4 b64 swizzled stores; PV unchanged layout.
__global__ __launch_bounds__(256) void k_attn(const bf16* __restrict__ qkv, const bf16* __restrict__ vt,
                                              bf16* __restrict__ y) {
  int bh = blockIdx.x;
  int b = bh / NHEAD, hh = bh % NHEAD;
  int qc = blockIdx.y ^ 3;                 // heavy-first: qcmod=192 blocks dispatch first
  int tid = threadIdx.x;
  int wave = tid >> 6, lane = tid & 63;
  int lrow = lane & 15, quad = lane >> 4;
  int sw = lrow & 7;
  int q0 = qc * 64 + wave * 16;
  int qmod = q0 & 255;
  int qcmod = (qc * 64) & 255;

  const size_t rstride = QKVN;
  const bf16* qbase = qkv + (size_t)(b * TSEQ) * rstride + hh * HDIM;
  const bf16* kbase = qbase + CDIM;
  const bf16* vtb = vt + (size_t)bh * HDIM * TSEQ;

  bf16x8 qf[2];
  #pragma unroll
  for (int kc = 0; kc < 2; kc++)
    qf[kc] = *(const bf16x8*)(qbase + (size_t)(q0 + lrow) * rstride + kc * 32 + quad * 8);

  f32x4 zz = {0.f, 0.f, 0.f, 0.f};
  f32x4 Oacc[4];
  #pragma unroll
  for (int j = 0; j < 4; j++) Oacc[j] = zz;
  float m = -1e30f, l = 0.f;

  __shared__ __align__(16) bf16 Ks[64 * 64];       // [key][d], swizzled chunks
  __shared__ __align__(16) bf16 Vs[64 * 64];       // [d][key] from vt, swizzled chunks
  __shared__ __align__(16) bf16 Pl[4][16 * 64];    // per-wave P [q][key], swizzled chunks

  for (int kt = 0; kt < 16; kt++) {
    int k0 = kt * 64;
    int kmod = k0 & 255;
    if (kmod > qcmod + 63) continue;       // block-uniform skip
    __syncthreads();
    #pragma unroll
    for (int i = 0; i < 2; i++) {
      int idx = i * 256 + tid;
      int row = idx >> 3, c = idx & 7;
      gld16(kbase + (size_t)(k0 + row) * rstride + ((c ^ (row & 7)) * 8), Ks + idx * 8);
      gld16(vtb + (size_t)row * TSEQ + k0 + ((c ^ (row & 7)) * 8), Vs + idx * 8);
    }
    __syncthreads();
    if (kmod > qmod + 15) continue;        // wave-uniform skip

    // S^T = K @ Q^T: lane holds q=lrow, keys sub*16+quad*4+r
    f32x4 s[4];
    #pragma unroll
    for (int sub = 0; sub < 4; sub++) {
      s[sub] = zz;
      #pragma unroll
      for (int kc = 0; kc < 2; kc++) {
        int g = kc * 4 + quad;
        bf16x8 kf = *(const bf16x8*)(Ks + (sub * 16 + lrow) * 64 + ((g ^ sw) * 8));
        s[sub] = __builtin_amdgcn_mfma_f32_16x16x32_bf16(kf, qf[kc], s[sub], 0, 0, 0);
      }
    }
    bool partial = (kmod + 63 > qmod);
    int qrel = qmod + lrow;
    #pragma unroll
    for (int sub = 0; sub < 4; sub++)
      #pragma unroll
      for (int r = 0; r < 4; r++) {
        float sv = s[sub][r] * 0.125f;     // 1/sqrt(64)
        if (partial && (kmod + sub * 16 + quad * 4 + r > qrel)) sv = -1e30f;
        s[sub][r] = sv;
      }
    // softmax: lane owns its q-row's 16 keys; quad-reduce via 2 shuffles
    float mx = fmaxf(fmaxf(fmaxf(s[0][0], s[0][1]), fmaxf(s[0][2], s[0][3])),
                     fmaxf(fmaxf(s[1][0], s[1][1]), fmaxf(s[1][2], s[1][3])));
    mx = fmaxf(mx, fmaxf(fmaxf(fmaxf(s[2][0], s[2][1]), fmaxf(s[2][2], s[2][3])),
                         fmaxf(fmaxf(s[3][0], s[3][1]), fmaxf(s[3][2], s[3][3]))));
    mx = fmaxf(mx, __shfl_xor(mx, 16, 64));
    mx = fmaxf(mx, __shfl_xor(mx, 32, 64));
    float mnew = fmaxf(m, mx);
    float alpha = __expf(m - mnew);
    m = mnew;
    float p[4][4];
    float rs = 0.f;
    #pragma unroll
    for (int sub = 0; sub < 4; sub++)
      #pragma unroll
      for (int r = 0; r < 4; r++) {
        p[sub][r] = __expf(s[sub][r] - mnew);
        rs += p[sub][r];
      }
    rs += __shfl_xor(rs, 16, 64);
    rs += __shfl_xor(rs, 32, 64);
    l = l * alpha + rs;
    // rescale O (alpha lives on lane lrow=q; fetch per C-row q=quad*4+r)
    #pragma unroll
    for (int r = 0; r < 4; r++) {
      float ar = __shfl(alpha, quad * 4 + r, 16);
      #pragma unroll
      for (int j = 0; j < 4; j++) Oacc[j][r] *= ar;
    }
    // P -> per-wave LDS: 4 x b64 swizzled stores (keys sub*16+quad*4+0..3 at row lrow)
    bf16* Pw = (bf16*)Pl[wave];
    #pragma unroll
    for (int sub = 0; sub < 4; sub++) {
      u16x4 o;
      o.x = (unsigned short)f2bs(p[sub][0]);
      o.y = (unsigned short)f2bs(p[sub][1]);
      o.z = (unsigned short)f2bs(p[sub][2]);
      o.w = (unsigned short)f2bs(p[sub][3]);
      int ch = sub * 2 + (quad >> 1);
      *(u16x4*)(Pw + lrow * 64 + ((ch ^ sw) * 8) + 4 * (quad & 1)) = o;
    }
    bf16x8 pf[2];
    #pragma unroll
    for (int kc = 0; kc < 2; kc++) {
      int g = kc * 4 + quad;
      pf[kc] = *(const bf16x8*)(Pw + lrow * 64 + ((g ^ sw) * 8));
    }
    #pragma unroll
    for (int j = 0; j < 4; j++)
      #pragma unroll
      for (int kc = 0; kc < 2; kc++) {
        int g = kc * 4 + quad;
        bf16x8 vf = *(const bf16x8*)(Vs + (j * 16 + lrow) * 64 + ((g ^ sw) * 8));
        Oacc[j] = __builtin_amdgcn_mfma_f32_16x16x32_bf16(pf[kc], vf, Oacc[j], 0, 0, 0);
      }
  }
  #pragma unroll
  for (int r = 0; r < 4; r++) {
    float linv = 1.0f / __shfl(l, quad * 4 + r, 16);
    bf16* yp = y + (size_t)(b * TSEQ + q0 + quad * 4 + r) * CDIM + hh * HDIM;
    #pragma unroll
    for (int j = 0; j < 4; j++)
      yp[j * 16 + lrow] = __float2bfloat16(Oacc[j][r] * linv);
  }
}

extern "C" void kernel_launch(void* const* d_in, const int* in_sizes, int n_in,
                              void* d_out, int out_size, void* d_ws, size_t ws_size,
                              hipStream_t stream) {
  const float* x    = (const float*)d_in[0];
  const float* ln1g = (const float*)d_in[1];
  const float* ln1b = (const float*)d_in[2];
  const float* Wq   = (const float*)d_in[3];
  const float* bq   = (const float*)d_in[4];
  const float* Wk   = (const float*)d_in[5];
  const float* bk   = (const float*)d_in[6];
  const float* Wv   = (const float*)d_in[7];
  const float* bv   = (const float*)d_in[8];
  const float* Wp   = (const float*)d_in[9];
  const float* bp   = (const float*)d_in[10];
  const float* ln2g = (const float*)d_in[11];
  const float* ln2b = (const float*)d_in[12];
  const float* W1   = (const float*)d_in[13];
  const float* b1   = (const float*)d_in[14];
  const float* W2   = (const float*)d_in[15];
  const float* b2   = (const float*)d_in[16];

  char* ws = (char*)d_ws;
  size_t off = 0;
  float* h    = (float*)(ws + off); off += (size_t)MROWS * CDIM * 4;
  bf16* a     = (bf16*)(ws + off);  off += (size_t)MROWS * CDIM * 2;
  bf16* qkvb  = (bf16*)(ws + off);  off += (size_t)MROWS * QKVN * 2;
  bf16* yb    = (bf16*)(ws + off);  off += (size_t)MROWS * CDIM * 2;
  bf16* vt    = (bf16*)(ws + off);  off += (size_t)4 * NHEAD * HDIM * TSEQ * 2;  // [48][64][1024]
  bf16* m1    = qkvb;  // alias: MLP hidden [4096,3072] overlays qkvb+yb (both dead by then)

  const size_t szQkv = (size_t)QKVN * CDIM * 2;
  const size_t szP   = (size_t)CDIM * CDIM * 2;
  const size_t szW1  = (size_t)CDIM * HID * 2;
  const size_t szW2  = (size_t)CDIM * HID * 2;
  const size_t szB   = (size_t)QKVN * 4;
  const size_t wlayer = szQkv + szP + szW1 + szW2 + szB;
  bool hoist = ws_size >= off + 4 * wlayer + 4096;
  int nW = hoist ? 4 : 1;

  bf16* wqkv  = (bf16*)(ws + off);  off += nW * szQkv;
  bf16* wtp   = (bf16*)(ws + off);  off += nW * szP;
  bf16* wt1   = (bf16*)(ws + off);  off += nW * szW1;
  bf16* wt2   = (bf16*)(ws + off);  off += nW * szW2;
  float* bqkv = (float*)(ws + off); off += nW * szB;

  int n = MROWS * CDIM;
  hipMemcpyAsync(h, x, (size_t)n * sizeof(float), hipMemcpyDeviceToDevice, stream);

  if (hoist)
    k_trans<<<dim3(4 * 1737), dim3(256), 0, stream>>>(Wq, Wk, Wv, Wp, W1, W2, bq, bk, bv,
                                                      wqkv, wtp, wt1, wt2, bqkv);

  for (int l = 0; l < 4; l++) {
    int wl = hoist ? l : 0;
    if (!hoist)
      k_trans<<<dim3(1737), dim3(256), 0, stream>>>(
          Wq + (size_t)l * CDIM * CDIM, Wk + (size_t)l * CDIM * CDIM,
          Wv + (size_t)l * CDIM * CDIM, Wp + (size_t)l * CDIM * CDIM,
          W1 + (size_t)l * CDIM * HID, W2 + (size_t)l * HID * CDIM,
          bq + (size_t)l * CDIM, bk + (size_t)l * CDIM, bv + (size_t)l * CDIM,
          wqkv, wtp, wt1, wt2, bqkv);
    const bf16* wqkvl = wqkv + (size_t)wl * QKVN * CDIM;
    const bf16* wtpl  = wtp  + (size_t)wl * CDIM * CDIM;
    const bf16* wt1l  = wt1  + (size_t)wl * CDIM * HID;
    const bf16* wt2l  = wt2  + (size_t)wl * CDIM * HID;
    const float* bqkvl = bqkv + (size_t)wl * QKVN;

    k_ln<<<dim3(MROWS / 4), dim3(256), 0, stream>>>(h, ln1g + l * CDIM, ln1b + l * CDIM, a);

    // QKV: q,k -> qkvb; v -> vt transposed
    k_gemmT<64, 128, 3><<<dim3(MROWS / 64, QKVN / 128), dim3(256), 0, stream>>>(
        a, wqkvl, bqkvl, qkvb, vt, MROWS, QKVN, CDIM);

    k_attn<<<dim3(4 * NHEAD, 16), dim3(256), 0, stream>>>(qkvb, vt, yb);

    // attn proj + residual: h += yb @ Wp^T + bp
    k_gemmT<64, 64, 2><<<dim3(MROWS / 64, CDIM / 64), dim3(256), 0, stream>>>(
        yb, wtpl, bp + (size_t)l * CDIM, h, nullptr, MROWS, CDIM, CDIM);

    k_ln<<<dim3(MROWS / 4), dim3(256), 0, stream>>>(h, ln2g + l * CDIM, ln2b + l * CDIM, a);

    // MLP up + gelu (tanh-form)
    k_gemmT<64, 128, 1><<<dim3(MROWS / 64, HID / 128), dim3(256), 0, stream>>>(
        a, wt1l, b1 + (size_t)l * HID, m1, nullptr, MROWS, HID, CDIM);

    // MLP down + residual
    k_gemmT<64, 64, 2><<<dim3(MROWS / 64, CDIM / 64), dim3(256), 0, stream>>>(
        m1, wt2l, b2 + (size_t)l * CDIM, h, nullptr, MROWS, CDIM, HID);
  }

  hipMemcpyAsync(d_out, h, (size_t)n * sizeof(float), hipMemcpyDeviceToDevice, stream);
}